// Round 1
// baseline (591.564 us; speedup 1.0000x reference)
//
#include <hip/hip_runtime.h>
#include <hip/hip_bf16.h>

typedef float f32x4 __attribute__((ext_vector_type(4)));
typedef short bf16x8 __attribute__((ext_vector_type(8)));
typedef unsigned short ushort_t;

// ---------- bf16 helpers (RNE) ----------
__device__ __forceinline__ ushort_t f2bf(float f) {
    union { float f; unsigned u; } v; v.f = f;
    unsigned r = v.u + 0x7fffu + ((v.u >> 16) & 1u);
    return (ushort_t)(r >> 16);
}
__device__ __forceinline__ float bf2f(ushort_t h) {
    union { unsigned u; float f; } v; v.u = ((unsigned)h) << 16;
    return v.f;
}

// ---------- cast fp32 -> bf16, 8 elems/thread ----------
__global__ __launch_bounds__(256) void cast_bf16_kernel(const float* __restrict__ src,
                                                        ushort_t* __restrict__ dst, long n) {
    long i = ((long)blockIdx.x * 256 + threadIdx.x) * 8;
    if (i >= n) return;
    float4 a = *(const float4*)(src + i);
    float4 b = *(const float4*)(src + i + 4);
    ushort_t o[8];
    o[0]=f2bf(a.x); o[1]=f2bf(a.y); o[2]=f2bf(a.z); o[3]=f2bf(a.w);
    o[4]=f2bf(b.x); o[5]=f2bf(b.y); o[6]=f2bf(b.z); o[7]=f2bf(b.w);
    *(bf16x8*)(dst + i) = *(bf16x8*)o;
}

// ---------- pack Wsr [C,C,2,2] -> bf16 B^T layout [c][tap*512+ci] ----------
__global__ __launch_bounds__(256) void pack_wsr_kernel(const float* __restrict__ w,
                                                       ushort_t* __restrict__ out) {
    int idx = blockIdx.x * 256 + threadIdx.x;   // 1048576 total
    int c = idx >> 11, k = idx & 2047;
    int tap = k >> 9, ci = k & 511;
    out[idx] = f2bf(w[c * 2048 + ci * 4 + tap]);
}

// ---------- generic 128x128 bf16 MFMA GEMM: C = A[M,K] * B[N,K]^T + bias ----------
// GATHER: A rows are SR-conv patches gathered from context_bf [B,4096,512]
// OMODE 0: bf16 out [M,N];  1: fp32 out [M,N];  2: bf16 out transposed to vT[B,8,64,1024]
template<bool GATHER, int OMODE>
__global__ __launch_bounds__(256) void gemm_bt(const ushort_t* __restrict__ A,
                                               const ushort_t* __restrict__ Bw,
                                               const float* __restrict__ bias,
                                               void* __restrict__ Cout,
                                               int M, int N, int K) {
    __shared__ __align__(16) ushort_t As[128][72];
    __shared__ __align__(16) ushort_t Bs[128][72];
    const int tid  = threadIdx.x;
    const int row0 = blockIdx.y * 128, col0 = blockIdx.x * 128;
    const int wave = tid >> 6, lane = tid & 63;
    const int rw = wave >> 1, cw = wave & 1;
    const int l15 = lane & 15, l4 = lane >> 4;

    f32x4 acc[4][4] = {};

    for (int k0 = 0; k0 < K; k0 += 64) {
        __syncthreads();
#pragma unroll
        for (int p = 0; p < 4; ++p) {
            int r  = p * 32 + (tid >> 3);
            int c8 = (tid & 7) * 8;
            bf16x8 av;
            if (GATHER) {
                int gr = row0 + r;
                int b = gr >> 10, m = gr & 1023;
                int mh = m >> 5, mw = m & 31;
                int tap = k0 >> 9;
                int kh = tap >> 1, kw = tap & 1;
                long base = ((long)(b * 4096 + (2 * mh + kh) * 64 + (2 * mw + kw))) * 512
                            + (k0 & 511);
                av = *(const bf16x8*)(A + base + c8);
            } else {
                av = *(const bf16x8*)(A + (long)(row0 + r) * K + k0 + c8);
            }
            *(bf16x8*)&As[r][c8] = av;
            bf16x8 bv = *(const bf16x8*)(Bw + (long)(col0 + r) * K + k0 + c8);
            *(bf16x8*)&Bs[r][c8] = bv;
        }
        __syncthreads();
#pragma unroll
        for (int ks = 0; ks < 2; ++ks) {
            bf16x8 af[4], bfr[4];
#pragma unroll
            for (int i = 0; i < 4; ++i)
                af[i] = *(const bf16x8*)&As[rw * 64 + i * 16 + l15][ks * 32 + l4 * 8];
#pragma unroll
            for (int j = 0; j < 4; ++j)
                bfr[j] = *(const bf16x8*)&Bs[cw * 64 + j * 16 + l15][ks * 32 + l4 * 8];
#pragma unroll
            for (int i = 0; i < 4; ++i)
#pragma unroll
                for (int j = 0; j < 4; ++j)
                    acc[i][j] = __builtin_amdgcn_mfma_f32_16x16x32_bf16(af[i], bfr[j],
                                                                        acc[i][j], 0, 0, 0);
        }
    }
    // epilogue: C/D layout col=lane&15, row=(lane>>4)*4+reg  [m89-verified]
#pragma unroll
    for (int i = 0; i < 4; ++i) {
#pragma unroll
        for (int j = 0; j < 4; ++j) {
            int col = col0 + cw * 64 + j * 16 + l15;
            float bv = bias[col];
#pragma unroll
            for (int r = 0; r < 4; ++r) {
                int row = row0 + rw * 64 + i * 16 + l4 * 4 + r;
                float v = acc[i][j][r] + bv;
                if (OMODE == 0) {
                    ((ushort_t*)Cout)[(long)row * N + col] = f2bf(v);
                } else if (OMODE == 1) {
                    ((float*)Cout)[(long)row * N + col] = v;
                } else {
                    int b = row >> 10, m = row & 1023;
                    int hh = col >> 6, dd = col & 63;
                    ((ushort_t*)Cout)[(((long)(b * 8 + hh) * 64 + dd) << 10) + m] = f2bf(v);
                }
            }
        }
    }
}

// ---------- in-place LayerNorm over rows of 512 (bf16), wave per row ----------
__global__ __launch_bounds__(256) void ln_kernel(ushort_t* __restrict__ data,
                                                 const float* __restrict__ g,
                                                 const float* __restrict__ be, int rows) {
    int wave = threadIdx.x >> 6, lane = threadIdx.x & 63;
    long row = (long)blockIdx.x * 4 + wave;
    if (row >= rows) return;
    ushort_t* p = data + row * 512 + lane * 8;
    bf16x8 raw = *(bf16x8*)p;
    ushort_t* rp = (ushort_t*)&raw;
    float v[8], s = 0.f, s2 = 0.f;
#pragma unroll
    for (int j = 0; j < 8; ++j) { v[j] = bf2f(rp[j]); s += v[j]; s2 += v[j] * v[j]; }
#pragma unroll
    for (int d = 1; d < 64; d <<= 1) { s += __shfl_xor(s, d); s2 += __shfl_xor(s2, d); }
    float mu  = s * (1.f / 512.f);
    float var = s2 * (1.f / 512.f) - mu * mu;
    float rs  = rsqrtf(var + 1e-5f);
    ushort_t o[8];
#pragma unroll
    for (int j = 0; j < 8; ++j) {
        int c = lane * 8 + j;
        o[j] = f2bf((v[j] - mu) * rs * g[c] + be[c]);
    }
    *(bf16x8*)p = *(bf16x8*)o;
}

// ---------- flash attention: block = (b, head, 64 q-rows), chunk M by 128 ----------
// Computes S^T = K·Q^T so softmax stats reduce via shfl_xor(16/32) and P packs to LDS
// in the A-operand layout for O = P·V (V pre-transposed in global: vt[B,8,64,1024]).
__global__ __launch_bounds__(256) void attn_kernel(const ushort_t* __restrict__ q,
                                                   const ushort_t* __restrict__ k,
                                                   const ushort_t* __restrict__ vt,
                                                   ushort_t* __restrict__ o) {
    __shared__ __align__(16) ushort_t Qs[64][72];
    __shared__ __align__(16) ushort_t Ks[128][72];
    __shared__ __align__(16) ushort_t Vs[64][136];
    __shared__ __align__(16) ushort_t Ps[64][136];
    __shared__ float mrun[64], lrun[64], alpha[64];
    __shared__ float wmax[4][64], wsum[4][64];

    const int tid = threadIdx.x;
    const int wave = tid >> 6, lane = tid & 63;
    const int l15 = lane & 15, l4 = lane >> 4;
    const int n0 = blockIdx.x * 64;
    const int hh = blockIdx.y;
    const int b  = blockIdx.z;
    const int aa = wave >> 1, ee = wave & 1;   // O: n-half, dd-half

    // stage Q, scaled by d^-0.5 = 0.125 (exact power-of-2 in bf16)
#pragma unroll
    for (int p = 0; p < 2; ++p) {
        int qi = p * 256 + tid;
        int r = qi >> 3, c8 = (qi & 7) * 8;
        bf16x8 v = *(const bf16x8*)(q + (((long)(b * 4096 + n0 + r) * 8 + hh) << 6) + c8);
        ushort_t* pv = (ushort_t*)&v;
        ushort_t ov[8];
#pragma unroll
        for (int j = 0; j < 8; ++j) ov[j] = f2bf(bf2f(pv[j]) * 0.125f);
        *(bf16x8*)&Qs[r][c8] = *(bf16x8*)ov;
    }
    if (tid < 64) { mrun[tid] = -1e30f; lrun[tid] = 0.f; }

    f32x4 oacc[2][2] = {};

    for (int c = 0; c < 8; ++c) {
        const int m0 = c * 128;
        __syncthreads();                                    // (a)
#pragma unroll
        for (int p = 0; p < 4; ++p) {                       // stage K chunk [128][64]
            int qi = p * 256 + tid;
            int r = qi >> 3, c8 = (qi & 7) * 8;
            bf16x8 v = *(const bf16x8*)(k + (((long)(b * 1024 + m0 + r) * 8 + hh) << 6) + c8);
            *(bf16x8*)&Ks[r][c8] = v;
        }
#pragma unroll
        for (int p = 0; p < 4; ++p) {                       // stage V^T chunk [64][128]
            int qi = p * 256 + tid;
            int dd = qi >> 4, c8 = (qi & 15) * 8;
            bf16x8 v = *(const bf16x8*)(vt + (((long)(b * 8 + hh) * 64 + dd) << 10) + m0 + c8);
            *(bf16x8*)&Vs[dd][c8] = v;
        }
        __syncthreads();                                    // (c)

        // S^T[m][n]: rows m = wave*32..+32, cols n = 0..64
        f32x4 s[2][4] = {};
#pragma unroll
        for (int ks = 0; ks < 2; ++ks) {
            bf16x8 af[2], bfr[4];
#pragma unroll
            for (int i = 0; i < 2; ++i)
                af[i] = *(const bf16x8*)&Ks[wave * 32 + i * 16 + l15][ks * 32 + l4 * 8];
#pragma unroll
            for (int j = 0; j < 4; ++j)
                bfr[j] = *(const bf16x8*)&Qs[j * 16 + l15][ks * 32 + l4 * 8];
#pragma unroll
            for (int i = 0; i < 2; ++i)
#pragma unroll
                for (int j = 0; j < 4; ++j)
                    s[i][j] = __builtin_amdgcn_mfma_f32_16x16x32_bf16(af[i], bfr[j],
                                                                      s[i][j], 0, 0, 0);
        }
        // chunk max per n (column of S^T)
        float pm[4];
#pragma unroll
        for (int j = 0; j < 4; ++j) {
            float m_ = -1e30f;
#pragma unroll
            for (int i = 0; i < 2; ++i)
#pragma unroll
                for (int r = 0; r < 4; ++r) m_ = fmaxf(m_, s[i][j][r]);
            m_ = fmaxf(m_, __shfl_xor(m_, 16));
            m_ = fmaxf(m_, __shfl_xor(m_, 32));
            pm[j] = m_;
        }
        if (lane < 16) {
#pragma unroll
            for (int j = 0; j < 4; ++j) wmax[wave][j * 16 + lane] = pm[j];
        }
        __syncthreads();                                    // (f)
        if (tid < 64) {
            float nm = fmaxf(fmaxf(fmaxf(wmax[0][tid], wmax[1][tid]),
                                   fmaxf(wmax[2][tid], wmax[3][tid])), mrun[tid]);
            alpha[tid] = __expf(mrun[tid] - nm);
            mrun[tid] = nm;
        }
        __syncthreads();                                    // (h)
        // P = exp(S - m_new): pack 4 consecutive m per lane -> 8B LDS writes
        float ps[4];
#pragma unroll
        for (int j = 0; j < 4; ++j) {
            float nm = mrun[j * 16 + l15];
            float sum = 0.f;
#pragma unroll
            for (int i = 0; i < 2; ++i) {
                ushort_t pk[4];
#pragma unroll
                for (int r = 0; r < 4; ++r) {
                    float e = __expf(s[i][j][r] - nm);
                    sum += e;
                    pk[r] = f2bf(e);
                }
                *(unsigned long long*)&Ps[j * 16 + l15][wave * 32 + i * 16 + l4 * 4] =
                    *(unsigned long long*)pk;
            }
            sum += __shfl_xor(sum, 16);
            sum += __shfl_xor(sum, 32);
            ps[j] = sum;
        }
        if (lane < 16) {
#pragma unroll
            for (int j = 0; j < 4; ++j) wsum[wave][j * 16 + lane] = ps[j];
        }
        // rescale O by alpha (visible since barrier h)
#pragma unroll
        for (int i = 0; i < 2; ++i)
#pragma unroll
            for (int r = 0; r < 4; ++r) {
                float al = alpha[aa * 32 + i * 16 + l4 * 4 + r];
                oacc[i][0][r] *= al;
                oacc[i][1][r] *= al;
            }
        __syncthreads();                                    // (j) P + wsum visible
        if (tid < 64)
            lrun[tid] = lrun[tid] * alpha[tid] +
                        wsum[0][tid] + wsum[1][tid] + wsum[2][tid] + wsum[3][tid];
        // O += P·V
#pragma unroll
        for (int ks = 0; ks < 4; ++ks) {
            bf16x8 af[2], bfr[2];
#pragma unroll
            for (int i = 0; i < 2; ++i)
                af[i] = *(const bf16x8*)&Ps[aa * 32 + i * 16 + l15][ks * 32 + l4 * 8];
#pragma unroll
            for (int j = 0; j < 2; ++j)
                bfr[j] = *(const bf16x8*)&Vs[ee * 32 + j * 16 + l15][ks * 32 + l4 * 8];
#pragma unroll
            for (int i = 0; i < 2; ++i)
#pragma unroll
                for (int j = 0; j < 2; ++j)
                    oacc[i][j] = __builtin_amdgcn_mfma_f32_16x16x32_bf16(af[i], bfr[j],
                                                                         oacc[i][j], 0, 0, 0);
        }
    }
    __syncthreads();
    // finalize: O /= l, store bf16 to [B,N,512]
#pragma unroll
    for (int i = 0; i < 2; ++i)
#pragma unroll
        for (int r = 0; r < 4; ++r) {
            int n = aa * 32 + i * 16 + l4 * 4 + r;
            float inv = 1.f / lrun[n];
#pragma unroll
            for (int j = 0; j < 2; ++j) {
                int dd = ee * 32 + j * 16 + l15;
                o[((long)(b * 4096 + n0 + n)) * 512 + hh * 64 + dd] =
                    f2bf(oacc[i][j][r] * inv);
            }
        }
}

extern "C" void kernel_launch(void* const* d_in, const int* in_sizes, int n_in,
                              void* d_out, int out_size, void* d_ws, size_t ws_size,
                              hipStream_t stream) {
    const float* x    = (const float*)d_in[0];
    const float* ctx  = (const float*)d_in[1];
    const float* Wq   = (const float*)d_in[2];
    const float* bq   = (const float*)d_in[3];
    const float* Wk   = (const float*)d_in[4];
    const float* bk   = (const float*)d_in[5];
    const float* Wv   = (const float*)d_in[6];
    const float* bv   = (const float*)d_in[7];
    const float* Wp   = (const float*)d_in[8];
    const float* bp   = (const float*)d_in[9];
    const float* Wsrk = (const float*)d_in[10];
    const float* bsrk = (const float*)d_in[11];
    const float* Wsrv = (const float*)d_in[12];
    const float* bsrv = (const float*)d_in[13];
    const float* gk   = (const float*)d_in[14];
    const float* bek  = (const float*)d_in[15];
    const float* gv   = (const float*)d_in[16];
    const float* bev  = (const float*)d_in[17];

    // workspace layout (elems of bf16)
    ushort_t* x_bf    = (ushort_t*)d_ws;
    ushort_t* ctx_bf  = x_bf    + 16777216;
    ushort_t* q_bf    = ctx_bf  + 16777216;
    ushort_t* at_bf   = q_bf    + 16777216;
    ushort_t* k_bf    = at_bf   + 16777216;
    ushort_t* vt_bf   = k_bf    + 4194304;
    ushort_t* convk   = vt_bf   + 4194304;   // LN in-place -> ctx_k
    ushort_t* convv   = convk   + 4194304;   // LN in-place -> ctx_v
    ushort_t* wq_bf   = convv   + 4194304;
    ushort_t* wk_bf   = wq_bf   + 262144;
    ushort_t* wv_bf   = wk_bf   + 262144;
    ushort_t* wp_bf   = wv_bf   + 262144;
    ushort_t* wsrk_p  = wp_bf   + 262144;
    ushort_t* wsrv_p  = wsrk_p  + 1048576;

    // 1) casts + weight packing
    cast_bf16_kernel<<<8192, 256, 0, stream>>>(x,   x_bf,   16777216);
    cast_bf16_kernel<<<8192, 256, 0, stream>>>(ctx, ctx_bf, 16777216);
    cast_bf16_kernel<<<128, 256, 0, stream>>>(Wq, wq_bf, 262144);
    cast_bf16_kernel<<<128, 256, 0, stream>>>(Wk, wk_bf, 262144);
    cast_bf16_kernel<<<128, 256, 0, stream>>>(Wv, wv_bf, 262144);
    cast_bf16_kernel<<<128, 256, 0, stream>>>(Wp, wp_bf, 262144);
    pack_wsr_kernel<<<4096, 256, 0, stream>>>(Wsrk, wsrk_p);
    pack_wsr_kernel<<<4096, 256, 0, stream>>>(Wsrv, wsrv_p);

    // 2) SR convs as gathered GEMMs (M=8192, N=512, K=2048)
    gemm_bt<true, 0><<<dim3(4, 64), 256, 0, stream>>>(ctx_bf, wsrk_p, bsrk, convk,
                                                      8192, 512, 2048);
    gemm_bt<true, 0><<<dim3(4, 64), 256, 0, stream>>>(ctx_bf, wsrv_p, bsrv, convv,
                                                      8192, 512, 2048);
    // 3) LayerNorms (in place)
    ln_kernel<<<2048, 256, 0, stream>>>(convk, gk, bek, 8192);
    ln_kernel<<<2048, 256, 0, stream>>>(convv, gv, bev, 8192);

    // 4) projections
    gemm_bt<false, 0><<<dim3(4, 256), 256, 0, stream>>>(x_bf,  wq_bf, bq, q_bf,
                                                        32768, 512, 512);
    gemm_bt<false, 0><<<dim3(4, 64), 256, 0, stream>>>(convk, wk_bf, bk, k_bf,
                                                       8192, 512, 512);
    gemm_bt<false, 2><<<dim3(4, 64), 256, 0, stream>>>(convv, wv_bf, bv, vt_bf,
                                                       8192, 512, 512);
    // 5) attention
    attn_kernel<<<dim3(64, 8, 8), 256, 0, stream>>>(q_bf, k_bf, vt_bf, at_bf);

    // 6) output projection -> fp32 d_out
    gemm_bt<false, 1><<<dim3(4, 256), 256, 0, stream>>>(at_bf, wp_bf, bp, d_out,
                                                        32768, 512, 512);
}